// Round 18
// baseline (383.466 us; speedup 1.0000x reference)
//
#include <hip/hip_runtime.h>
#include <hip/hip_bf16.h>

#define MUL 32
#define SCAN_CH 1024

typedef _Float16 f16x8 __attribute__((ext_vector_type(8)));
typedef float f32x4 __attribute__((ext_vector_type(4)));

static __device__ __forceinline__ float silu_f(float z) {
    return z / (1.0f + __expf(-z));
}

static __device__ __forceinline__ int lbound(const int* __restrict__ rp,
                                             int cnt, int target) {
    int lo = 0, hi = cnt;              // first idx with rp[idx] >= target
    while (lo < hi) {
        const int mid = (lo + hi) >> 1;
        if (rp[mid] < target) lo = mid + 1; else hi = mid;
    }
    return lo;
}

// ---------------------------------------------------------------------------
// Kernel A: per-node pre-pass, wave-per-node, barrier-free. (r14-r17 verified)
// ---------------------------------------------------------------------------
__global__ __launch_bounds__(256) void node_pre_kernel(
    const float* __restrict__ x, const float* __restrict__ attr,
    const float* __restrict__ Wsc0, const float* __restrict__ Wsc1,
    const float* __restrict__ Wl10, const float* __restrict__ Wl11,
    float* __restrict__ sc_out, _Float16* __restrict__ y_out, int N)
{
    __shared__ float sX[4][128];
    const int tid = threadIdx.x;
    const int wid = tid >> 6, L = tid & 63;
    float* xs = sX[wid];
    const float inv = 0.17677669529663687f; // 1/sqrt(32)

    const bool t0 = (L < 32);
    const int i1 = t0 ? 0 : (L - 32);
    const int v1 = i1 / 3, c1 = i1 - v1 * 3;
    const int i2 = L + 32;
    const int v2 = i2 / 3, c2 = i2 - v2 * 3;

    const int xb1 = t0 ? 0 : (32 + c1);
    const int xst1 = t0 ? 1 : 3;

    float wA[32], wB[32], wC[32], wD[32];
#pragma unroll
    for (int u = 0; u < 32; ++u) {
        wA[u] = t0 ? Wsc0[u * 32 + L] : Wsc1[u * 32 + v1];
        wB[u] = t0 ? Wl10[u * 32 + L] : Wl11[u * 32 + v1];
        wC[u] = Wsc1[u * 32 + v2];
        wD[u] = Wl11[u * 32 + v2];
    }

    const int stride = gridDim.x * 4;
    for (int n = blockIdx.x * 4 + wid; n < N; n += stride) {
        xs[L]      = x[(size_t)n * 128 + L];
        xs[64 + L] = x[(size_t)n * 128 + 64 + L];
        const float scale = inv * attr[n];
        float a0 = 0.f, a1 = 0.f, b0 = 0.f, b1 = 0.f;
#pragma unroll
        for (int u = 0; u < 32; ++u) {
            const float xv1 = xs[xb1 + u * xst1];
            const float xv2 = xs[32 + u * 3 + c2];
            a0 += xv1 * wA[u];
            a1 += xv1 * wB[u];
            b0 += xv2 * wC[u];
            b1 += xv2 * wD[u];
        }
        sc_out[(size_t)n * 128 + L]      = a0 * scale;
        sc_out[(size_t)n * 128 + 64 + L] = b0 * scale;
        y_out [(size_t)n * 128 + L]      = (_Float16)(a1 * scale);
        y_out [(size_t)n * 128 + 64 + L] = (_Float16)(b1 * scale);
    }
}

// ---------------------------------------------------------------------------
// CSR build: histogram -> 3-phase coalesced scan -> fill. (r17-verified)
// ---------------------------------------------------------------------------
__global__ void hist_kernel(const int* __restrict__ edst, int* __restrict__ deg, int E)
{
    int i = blockIdx.x * blockDim.x + threadIdx.x;
    const int stride = gridDim.x * blockDim.x;
    for (; i < E; i += stride) atomicAdd(&deg[edst[i]], 1);
}

__global__ __launch_bounds__(256) void scanA_kernel(
    const int* __restrict__ deg, int* __restrict__ bsum, int N)
{
    __shared__ int red[256];
    const int t = threadIdx.x, b = blockIdx.x;
    const int base = b * SCAN_CH;
    int s = 0;
#pragma unroll
    for (int k = 0; k < 4; ++k) {
        const int idx = base + t + k * 256;
        if (idx < N) s += deg[idx];
    }
    red[t] = s;
    __syncthreads();
    for (int off = 128; off; off >>= 1) {
        if (t < off) red[t] += red[t + off];
        __syncthreads();
    }
    if (t == 0) bsum[b] = red[0];
}

__global__ __launch_bounds__(256) void scanB_kernel(
    const int* __restrict__ bsum, int* __restrict__ boff, int NB)
{
    __shared__ int s[256];
    const int t = threadIdx.x;
    const int v = (t < NB) ? bsum[t] : 0;
    s[t] = v;
    __syncthreads();
    for (int off = 1; off < 256; off <<= 1) {
        const int add = (t >= off) ? s[t - off] : 0;
        __syncthreads();
        s[t] += add;
        __syncthreads();
    }
    if (t < NB) boff[t] = s[t] - v;
}

__global__ __launch_bounds__(256) void scanC_kernel(
    const int* __restrict__ deg, const int* __restrict__ boff,
    int* __restrict__ row_ptr, int N)
{
    __shared__ int ts[256];
    const int t = threadIdx.x, b = blockIdx.x;
    const int base = b * SCAN_CH + t * 4;
    int d0 = 0, d1 = 0, d2 = 0, d3 = 0;
    if (base + 0 < N) d0 = deg[base + 0];
    if (base + 1 < N) d1 = deg[base + 1];
    if (base + 2 < N) d2 = deg[base + 2];
    if (base + 3 < N) d3 = deg[base + 3];
    const int tsum = d0 + d1 + d2 + d3;
    ts[t] = tsum;
    __syncthreads();
    for (int off = 1; off < 256; off <<= 1) {
        const int add = (t >= off) ? ts[t - off] : 0;
        __syncthreads();
        ts[t] += add;
        __syncthreads();
    }
    int run = boff[b] + ts[t] - tsum;
    if (base + 0 <= N) row_ptr[base + 0] = run;
    run += d0;
    if (base + 1 <= N) row_ptr[base + 1] = run;
    run += d1;
    if (base + 2 <= N) row_ptr[base + 2] = run;
    run += d2;
    if (base + 3 <= N) row_ptr[base + 3] = run;
}

__global__ void fill_kernel(
    const int* __restrict__ esrc, const int* __restrict__ edst,
    const float* __restrict__ esh,
    const int* __restrict__ row_ptr, int* __restrict__ cur,
    int* __restrict__ csr2edge, int* __restrict__ src_s, float4* __restrict__ sh_s,
    int E)
{
    int i = blockIdx.x * blockDim.x + threadIdx.x;
    const int stride = gridDim.x * blockDim.x;
    for (; i < E; i += stride) {
        const int d = edst[i];
        const int p = row_ptr[d] + atomicAdd(&cur[d], 1);
        csr2edge[p] = i;
        src_s[p] = esrc[i];
        sh_s[p] = *(const float4*)&esh[(size_t)i * 4];
    }
}

// ---------------------------------------------------------------------------
// Kernel B (FUSED): per wave, a node-aligned contiguous CSR range.
//  For each 16-slot batch: MLP via MFMA (r17-verified pipeline) -> Hw; then
//  walk the batch edge-by-edge, accumulate the tensor product per lane
//  (r11-verified ACC_EDGE), and at node boundaries write pre-divided mid
//  (f16) to global. w never touches global memory.
// ---------------------------------------------------------------------------
__global__ __launch_bounds__(512) void edge_fused_kernel(
    const float* __restrict__ escal, const int* __restrict__ csr2edge,
    const float* __restrict__ Wfc1, const float* __restrict__ Wfc2,
    const int* __restrict__ src_s, const float4* __restrict__ sh_s,
    const int* __restrict__ row_ptr, const _Float16* __restrict__ y,
    _Float16* __restrict__ mid_g, int N, int E)
{
    __shared__ _Float16 sW2T[128 * 128];   // 32 KB, [col][k] swizzled
    __shared__ _Float16 sH[8][16 * 128];   // 4 KB per wave

    const int tid = threadIdx.x;
    const int wid = tid >> 6;              // wave 0..7
    const int l   = tid & 63;
    const int c16 = l & 15;
    const int kq  = l >> 4;

    _Float16* Hw = sH[wid];

    {
        int* z2 = (int*)sW2T;
        for (int i = tid; i < 128 * 128 / 2; i += 512) z2[i] = 0;
    }
    __syncthreads();
    for (int i = tid; i < 100 * 128; i += 512) {
        const int k = i >> 7, col = i & 127;
        sW2T[col * 128 + (k ^ ((col & 7) << 3))] = (_Float16)Wfc2[i];
    }

    f16x8 bW1[7];
#pragma unroll
    for (int cb = 0; cb < 7; ++cb) {
        const int col = cb * 16 + c16;
#pragma unroll
        for (int j = 0; j < 8; ++j) {
            const int k = kq * 8 + j;
            bW1[cb][j] = (k < 10 && col < 100) ? (_Float16)Wfc1[k * 100 + col]
                                               : (_Float16)0.f;
        }
    }
#pragma unroll
    for (int r = 0; r < 4; ++r) {
        const int row = kq * 4 + r;
        const int col = 112 + c16;
        Hw[row * 128 + (col ^ ((row & 7) << 3))] = (_Float16)0.f;
    }
    __syncthreads();   // W2T visible; no barriers after this

    const float inv_s10 = 0.31622776601683794f; // 1/sqrt(10)
    const float inv_s3  = 0.5773502691896258f;  // 1/sqrt(3)

    // per-lane accumulate constants (r11-verified mapping)
    const bool hi = (l >= 32);
    const int u = l & 31;
    const int wAi = hi ? 32 + u : u;
    const int wBi = hi ? 96 + u : 64 + u;
    const int yi0 = hi ? 32 + 3 * u + 0 : u;
    const int yi1 = hi ? 32 + 3 * u + 1 : u;
    const int yi2 = hi ? 32 + 3 * u + 2 : u;
    const float mulA = hi ? inv_s3 : 1.0f;

    // ---- wave's node-aligned CSR range ----
    const int W = gridDim.x * 8;
    const int k_w = blockIdx.x * 8 + wid;
    const int tgt0 = (int)((long)k_w * E / W);
    const int tgt1 = (int)((long)(k_w + 1) * E / W);
    const int nlo = lbound(row_ptr, N + 1, tgt0);
    const int nhi = lbound(row_ptr, N + 1, tgt1);
    if (nlo >= nhi) return;
    const int jstart = row_ptr[nlo];
    const int jend   = row_ptr[nhi];
    if (jstart >= jend) return;

    int n = nlo;
    while (n < nhi && row_ptr[n + 1] == row_ptr[n]) ++n;
    int jhi_n = row_ptr[n + 1];

    float accA = 0.f, ac1 = 0.f, ac2 = 0.f, ac3 = 0.f;

    // prologue: gathered A1 for first batch
    f16x8 a1;
    {
        const int ge = jstart + c16;
        const int ee = (ge < jend) ? csr2edge[ge] : 0;
#pragma unroll
        for (int j = 0; j < 8; ++j) {
            const int k = kq * 8 + j;
            a1[j] = (k < 10 && ge < jend)
                    ? (_Float16)escal[(size_t)ee * 10 + k] : (_Float16)0.f;
        }
    }

    for (int bb = jstart; bb < jend; bb += 16) {
        // ---- phase 1: h -> Hw (swizzled) ----
#pragma unroll
        for (int cb = 0; cb < 7; ++cb) {
            f32x4 z = {0.f, 0.f, 0.f, 0.f};
            z = __builtin_amdgcn_mfma_f32_16x16x32_f16(a1, bW1[cb], z, 0, 0, 0);
#pragma unroll
            for (int r = 0; r < 4; ++r) {
                const int row = kq * 4 + r;
                const int col = cb * 16 + c16;
                const float h = silu_f(z[r] * inv_s10) * 0.1f;
                Hw[row * 128 + (col ^ ((row & 7) << 3))] = (_Float16)h;
            }
        }

        // ---- prefetch next batch's A1 (contiguous slots) ----
        f16x8 a1n;
        {
            const int ge = bb + 16 + c16;
            const int ee = (ge < jend) ? csr2edge[ge] : 0;
#pragma unroll
            for (int j = 0; j < 8; ++j) {
                const int k = kq * 8 + j;
                a1n[j] = (k < 10 && ge < jend)
                         ? (_Float16)escal[(size_t)ee * 10 + k] : (_Float16)0.f;
            }
        }

        // ---- phase 2: w = H @ W2 (32 MFMA) ----
        f32x4 acw0 = {0.f,0.f,0.f,0.f}, acw1 = {0.f,0.f,0.f,0.f};
        f32x4 acw2 = {0.f,0.f,0.f,0.f}, acw3 = {0.f,0.f,0.f,0.f};
        f32x4 acw4 = {0.f,0.f,0.f,0.f}, acw5 = {0.f,0.f,0.f,0.f};
        f32x4 acw6 = {0.f,0.f,0.f,0.f}, acw7 = {0.f,0.f,0.f,0.f};
#pragma unroll
        for (int kk = 0; kk < 4; ++kk) {
            const f16x8 a2 = *(const f16x8*)&Hw[c16 * 128 +
                                ((kk * 32 + kq * 8) ^ ((c16 & 7) << 3))];
#define BFRAG(CB) (*(const f16x8*)&sW2T[((CB) * 16 + c16) * 128 + \
                       ((kk * 32 + kq * 8) ^ ((c16 & 7) << 3))])
            acw0 = __builtin_amdgcn_mfma_f32_16x16x32_f16(a2, BFRAG(0), acw0, 0, 0, 0);
            acw1 = __builtin_amdgcn_mfma_f32_16x16x32_f16(a2, BFRAG(1), acw1, 0, 0, 0);
            acw2 = __builtin_amdgcn_mfma_f32_16x16x32_f16(a2, BFRAG(2), acw2, 0, 0, 0);
            acw3 = __builtin_amdgcn_mfma_f32_16x16x32_f16(a2, BFRAG(3), acw3, 0, 0, 0);
            acw4 = __builtin_amdgcn_mfma_f32_16x16x32_f16(a2, BFRAG(4), acw4, 0, 0, 0);
            acw5 = __builtin_amdgcn_mfma_f32_16x16x32_f16(a2, BFRAG(5), acw5, 0, 0, 0);
            acw6 = __builtin_amdgcn_mfma_f32_16x16x32_f16(a2, BFRAG(6), acw6, 0, 0, 0);
            acw7 = __builtin_amdgcn_mfma_f32_16x16x32_f16(a2, BFRAG(7), acw7, 0, 0, 0);
#undef BFRAG
        }

        // ---- stage w into Hw (h dead; per-wave in-order LDS) ----
#define STAGE_CB(CB, ACC)                                                     \
        {                                                                     \
            _Pragma("unroll")                                                 \
            for (int r = 0; r < 4; ++r) {                                     \
                const int row = kq * 4 + r;                                   \
                const int col = (CB) * 16 + c16;                              \
                Hw[row * 128 + (col ^ ((row & 7) << 3))] = (_Float16)(ACC)[r];\
            }                                                                 \
        }
        STAGE_CB(0, acw0) STAGE_CB(1, acw1) STAGE_CB(2, acw2) STAGE_CB(3, acw3)
        STAGE_CB(4, acw4) STAGE_CB(5, acw5) STAGE_CB(6, acw6) STAGE_CB(7, acw7)
#undef STAGE_CB

        // ---- accumulate tensor product; node epilogues at boundaries ----
        const int nb = (jend - bb < 16) ? (jend - bb) : 16;
        for (int e = 0; e < nb; ++e) {
            const int jj = bb + e;
            const int sa = src_s[jj];
            const float4 sh = sh_s[jj];
            const int sw = (e & 7) << 3;
            const float wAv = (float)Hw[e * 128 + (wAi ^ sw)];
            const float wBv = (float)Hw[e * 128 + (wBi ^ sw)];
            const _Float16* yr = y + (size_t)sa * 128;
            const float q0 = (float)yr[yi0];
            const float q1 = (float)yr[yi1];
            const float q2 = (float)yr[yi2];
            const float sA0 = hi ? sh.y : sh.x;
            const float sA1 = hi ? sh.z : 0.f;
            const float sA2 = hi ? sh.w : 0.f;
            const float b1s = hi ? sh.x : sh.y;
            const float b2s = hi ? sh.x : sh.z;
            const float b3s = hi ? sh.x : sh.w;
            accA += wAv * mulA * (q0 * sA0 + q1 * sA1 + q2 * sA2);
            ac1  += wBv * q0 * b1s;
            ac2  += wBv * q1 * b2s;
            ac3  += wBv * q2 * b3s;

            if (jj + 1 == jhi_n) {
                const int rlo = row_ptr[n];
                const float rdeg = 1.0f / (float)(jhi_n - rlo);
                _Float16* mg = mid_g + (size_t)n * 256;
                mg[l]       = (_Float16)(accA * rdeg);
                mg[64 + l]  = (_Float16)(ac1 * rdeg);
                mg[128 + l] = (_Float16)(ac2 * rdeg);
                mg[192 + l] = (_Float16)(ac3 * rdeg);
                accA = ac1 = ac2 = ac3 = 0.f;
                ++n;
                while (n < nhi && row_ptr[n + 1] == row_ptr[n]) ++n;
                if (n < nhi) jhi_n = row_ptr[n + 1];
            }
        }

        a1 = a1n;
    }
}

// ---------------------------------------------------------------------------
// Kernel C: node post. mid (pre-divided, f16) -> alpha/conv -> out += .
// (epilogue code verbatim from r11-verified gather_post)
// ---------------------------------------------------------------------------
__global__ __launch_bounds__(256) void node_post_kernel(
    const _Float16* __restrict__ mid_g, const int* __restrict__ row_ptr,
    const float* __restrict__ attr,
    const float* __restrict__ Wl20, const float* __restrict__ Wl21,
    const float* __restrict__ Walpha,
    float* __restrict__ out, int N)
{
    __shared__ float sW0[64 * 32];
    __shared__ float sW1[64 * 32];
    __shared__ float sWa[64];
    __shared__ float sMid[4][256];

    const int tid = threadIdx.x;
    for (int i = tid; i < 64 * 32; i += 256) {
        sW0[i] = Wl20[i];
        sW1[i] = Wl21[i];
    }
    if (tid < 64) sWa[tid] = Walpha[tid];
    __syncthreads();

    const int wid = tid >> 6;
    const int L   = tid & 63;
    const bool hi = (L >= 32);

    const int o1m = L - 32;
    const int v1 = hi ? o1m / 3 : 0;
    const int c1 = hi ? o1m - v1 * 3 : 0;
    const int o2m = L + 32;
    const int v2 = o2m / 3;
    const int c2 = o2m - v2 * 3;
    const float* wcol1 = hi ? (sW1 + v1) : (sW0 + L);
    const float* wcol2 = sW1 + v2;

    float* midw = &sMid[wid][0];
    const float* msrc1c = hi ? (midw + 64 + c1 * 64) : midw;
    const float* msrc2c = midw + 64 + c2 * 64;

    const int waves_glob = gridDim.x * 4;
    for (int n = blockIdx.x * 4 + wid; n < N; n += waves_glob) {
        const int deg = row_ptr[n + 1] - row_ptr[n];
        if (deg <= 0) continue;

        const _Float16* mg = mid_g + (size_t)n * 256;
        const float m0 = (float)mg[L];
        const float m1 = (float)mg[64 + L];
        const float m2 = (float)mg[128 + L];
        const float m3 = (float)mg[192 + L];
        const float a = attr[n];

        float term = m0 * sWa[L];
#pragma unroll
        for (int off = 32; off; off >>= 1) term += __shfl_xor(term, off);
        const float alpha = term * 0.125f * a;

        midw[L]       = m0;
        midw[64 + L]  = m1;
        midw[128 + L] = m2;
        midw[192 + L] = m3;

        float cv1 = 0.f, cv2 = 0.f;
#pragma unroll
        for (int kk = 0; kk < 16; ++kk) {
            const float4 mm1 = *(const float4*)&msrc1c[4 * kk];
            const float4 mm2 = *(const float4*)&msrc2c[4 * kk];
            cv1 += mm1.x * wcol1[(4 * kk + 0) * 32] + mm1.y * wcol1[(4 * kk + 1) * 32]
                 + mm1.z * wcol1[(4 * kk + 2) * 32] + mm1.w * wcol1[(4 * kk + 3) * 32];
            cv2 += mm2.x * wcol2[(4 * kk + 0) * 32] + mm2.y * wcol2[(4 * kk + 1) * 32]
                 + mm2.z * wcol2[(4 * kk + 2) * 32] + mm2.w * wcol2[(4 * kk + 3) * 32];
        }
        const float f = alpha * 0.125f * a;
        const size_t ob = (size_t)n * 128;
        out[ob + L]      += f * cv1;
        out[ob + 64 + L] += f * cv2;
    }
}

extern "C" void kernel_launch(void* const* d_in, const int* in_sizes, int n_in,
                              void* d_out, int out_size, void* d_ws, size_t ws_size,
                              hipStream_t stream)
{
    const float* x      = (const float*)d_in[0];
    const float* attr   = (const float*)d_in[1];
    const int*   esrc   = (const int*)  d_in[2];
    const int*   edst   = (const int*)  d_in[3];
    const float* esh    = (const float*)d_in[4];
    const float* escal  = (const float*)d_in[5];
    const float* Wfc1   = (const float*)d_in[6];
    const float* Wfc2   = (const float*)d_in[7];
    const float* Wsc0   = (const float*)d_in[8];
    const float* Wsc1   = (const float*)d_in[9];
    const float* Wl10   = (const float*)d_in[10];
    const float* Wl11   = (const float*)d_in[11];
    const float* Wl20   = (const float*)d_in[12];
    const float* Wl21   = (const float*)d_in[13];
    const float* Walpha = (const float*)d_in[14];

    const int N = in_sizes[1];
    const int E = in_sizes[2];
    float* out = (float*)d_out;

    // ws: y(f16) | row_ptr | deg | cur | bsum | boff | csr2edge | src_s |
    //     [align16] sh_s | mid_g(f16)
    char* p = (char*)d_ws;
    _Float16* y   = (_Float16*)p; p += (size_t)N * 128 * sizeof(_Float16);
    int* row_ptr  = (int*)p;      p += (size_t)(N + 1) * sizeof(int);
    int* deg      = (int*)p;      p += (size_t)N * sizeof(int);
    int* cur      = (int*)p;      p += (size_t)N * sizeof(int);
    int* bsum     = (int*)p;      p += 256 * sizeof(int);
    int* boff     = (int*)p;      p += 256 * sizeof(int);
    int* csr2edge = (int*)p;      p += (size_t)E * sizeof(int);
    int* src_s    = (int*)p;      p += (size_t)E * sizeof(int);
    p = (char*)(((uintptr_t)p + 15) & ~(uintptr_t)15);
    float4* sh_s  = (float4*)p;   p += (size_t)E * sizeof(float4);
    _Float16* mid_g = (_Float16*)p;

    const int NB = (N + SCAN_CH) / SCAN_CH;

    hipMemsetAsync(deg, 0, (size_t)2 * N * sizeof(int), stream);

    node_pre_kernel<<<1024, 256, 0, stream>>>(x, attr, Wsc0, Wsc1, Wl10, Wl11,
                                              out, y, N);
    hist_kernel<<<512, 256, 0, stream>>>(edst, deg, E);
    scanA_kernel<<<NB, 256, 0, stream>>>(deg, bsum, N);
    scanB_kernel<<<1, 256, 0, stream>>>(bsum, boff, NB);
    scanC_kernel<<<NB, 256, 0, stream>>>(deg, boff, row_ptr, N);
    fill_kernel<<<512, 256, 0, stream>>>(esrc, edst, esh, row_ptr, cur,
                                         csr2edge, src_s, sh_s, E);
    edge_fused_kernel<<<512, 512, 0, stream>>>(escal, csr2edge, Wfc1, Wfc2,
                                               src_s, sh_s, row_ptr, y,
                                               mid_g, N, E);
    node_post_kernel<<<1024, 256, 0, stream>>>(mid_g, row_ptr, attr,
                                               Wl20, Wl21, Walpha, out, N);
}

// Round 19
// 252.648 us; speedup vs baseline: 1.5178x; 1.5178x over previous
//
#include <hip/hip_runtime.h>
#include <hip/hip_bf16.h>

#define MUL 32
#define SCAN_CH 1024

typedef _Float16 f16x8 __attribute__((ext_vector_type(8)));
typedef float f32x4 __attribute__((ext_vector_type(4)));

static __device__ __forceinline__ float silu_f(float z) {
    return z / (1.0f + __expf(-z));
}

// ---------------------------------------------------------------------------
// Kernel A: per-node pre-pass, wave-per-node, barrier-free. (r14-r17 verified)
// ---------------------------------------------------------------------------
__global__ __launch_bounds__(256) void node_pre_kernel(
    const float* __restrict__ x, const float* __restrict__ attr,
    const float* __restrict__ Wsc0, const float* __restrict__ Wsc1,
    const float* __restrict__ Wl10, const float* __restrict__ Wl11,
    float* __restrict__ sc_out, _Float16* __restrict__ y_out, int N)
{
    __shared__ float sX[4][128];
    const int tid = threadIdx.x;
    const int wid = tid >> 6, L = tid & 63;
    float* xs = sX[wid];
    const float inv = 0.17677669529663687f; // 1/sqrt(32)

    const bool t0 = (L < 32);
    const int i1 = t0 ? 0 : (L - 32);
    const int v1 = i1 / 3, c1 = i1 - v1 * 3;
    const int i2 = L + 32;
    const int v2 = i2 / 3, c2 = i2 - v2 * 3;

    const int xb1 = t0 ? 0 : (32 + c1);
    const int xst1 = t0 ? 1 : 3;

    float wA[32], wB[32], wC[32], wD[32];
#pragma unroll
    for (int u = 0; u < 32; ++u) {
        wA[u] = t0 ? Wsc0[u * 32 + L] : Wsc1[u * 32 + v1];
        wB[u] = t0 ? Wl10[u * 32 + L] : Wl11[u * 32 + v1];
        wC[u] = Wsc1[u * 32 + v2];
        wD[u] = Wl11[u * 32 + v2];
    }

    const int stride = gridDim.x * 4;
    for (int n = blockIdx.x * 4 + wid; n < N; n += stride) {
        xs[L]      = x[(size_t)n * 128 + L];
        xs[64 + L] = x[(size_t)n * 128 + 64 + L];
        const float scale = inv * attr[n];
        float a0 = 0.f, a1 = 0.f, b0 = 0.f, b1 = 0.f;
#pragma unroll
        for (int u = 0; u < 32; ++u) {
            const float xv1 = xs[xb1 + u * xst1];
            const float xv2 = xs[32 + u * 3 + c2];
            a0 += xv1 * wA[u];
            a1 += xv1 * wB[u];
            b0 += xv2 * wC[u];
            b1 += xv2 * wD[u];
        }
        sc_out[(size_t)n * 128 + L]      = a0 * scale;
        sc_out[(size_t)n * 128 + 64 + L] = b0 * scale;
        y_out [(size_t)n * 128 + L]      = (_Float16)(a1 * scale);
        y_out [(size_t)n * 128 + 64 + L] = (_Float16)(b1 * scale);
    }
}

// ---------------------------------------------------------------------------
// CSR build: histogram -> 3-phase coalesced scan -> fill. (r17-verified)
// ---------------------------------------------------------------------------
__global__ void hist_kernel(const int* __restrict__ edst, int* __restrict__ deg, int E)
{
    int i = blockIdx.x * blockDim.x + threadIdx.x;
    const int stride = gridDim.x * blockDim.x;
    for (; i < E; i += stride) atomicAdd(&deg[edst[i]], 1);
}

__global__ __launch_bounds__(256) void scanA_kernel(
    const int* __restrict__ deg, int* __restrict__ bsum, int N)
{
    __shared__ int red[256];
    const int t = threadIdx.x, b = blockIdx.x;
    const int base = b * SCAN_CH;
    int s = 0;
#pragma unroll
    for (int k = 0; k < 4; ++k) {
        const int idx = base + t + k * 256;
        if (idx < N) s += deg[idx];
    }
    red[t] = s;
    __syncthreads();
    for (int off = 128; off; off >>= 1) {
        if (t < off) red[t] += red[t + off];
        __syncthreads();
    }
    if (t == 0) bsum[b] = red[0];
}

__global__ __launch_bounds__(256) void scanB_kernel(
    const int* __restrict__ bsum, int* __restrict__ boff, int NB)
{
    __shared__ int s[256];
    const int t = threadIdx.x;
    const int v = (t < NB) ? bsum[t] : 0;
    s[t] = v;
    __syncthreads();
    for (int off = 1; off < 256; off <<= 1) {
        const int add = (t >= off) ? s[t - off] : 0;
        __syncthreads();
        s[t] += add;
        __syncthreads();
    }
    if (t < NB) boff[t] = s[t] - v;
}

__global__ __launch_bounds__(256) void scanC_kernel(
    const int* __restrict__ deg, const int* __restrict__ boff,
    int* __restrict__ row_ptr, int N)
{
    __shared__ int ts[256];
    const int t = threadIdx.x, b = blockIdx.x;
    const int base = b * SCAN_CH + t * 4;
    int d0 = 0, d1 = 0, d2 = 0, d3 = 0;
    if (base + 0 < N) d0 = deg[base + 0];
    if (base + 1 < N) d1 = deg[base + 1];
    if (base + 2 < N) d2 = deg[base + 2];
    if (base + 3 < N) d3 = deg[base + 3];
    const int tsum = d0 + d1 + d2 + d3;
    ts[t] = tsum;
    __syncthreads();
    for (int off = 1; off < 256; off <<= 1) {
        const int add = (t >= off) ? ts[t - off] : 0;
        __syncthreads();
        ts[t] += add;
        __syncthreads();
    }
    int run = boff[b] + ts[t] - tsum;
    if (base + 0 <= N) row_ptr[base + 0] = run;
    run += d0;
    if (base + 1 <= N) row_ptr[base + 1] = run;
    run += d1;
    if (base + 2 <= N) row_ptr[base + 2] = run;
    run += d2;
    if (base + 3 <= N) row_ptr[base + 3] = run;
}

__global__ void fill_kernel(
    const int* __restrict__ esrc, const int* __restrict__ edst,
    const float* __restrict__ esh,
    const int* __restrict__ row_ptr, int* __restrict__ cur,
    int* __restrict__ csr2edge, int* __restrict__ src_s, float4* __restrict__ sh_s,
    int E)
{
    int i = blockIdx.x * blockDim.x + threadIdx.x;
    const int stride = gridDim.x * blockDim.x;
    for (; i < E; i += stride) {
        const int d = edst[i];
        const int p = row_ptr[d] + atomicAdd(&cur[d], 1);
        csr2edge[p] = i;
        src_s[p] = esrc[i];
        sh_s[p] = *(const float4*)&esh[(size_t)i * 4];
    }
}

// ---------------------------------------------------------------------------
// Kernel B: edge MLP -> w (f16, CSR-slot order, sequential stores). (r17,
// 88 us verified: 512 threads, 8 waves share W2T, 2 blocks/CU, grid 512)
// ---------------------------------------------------------------------------
__global__ __launch_bounds__(512) void edge_w_kernel(
    const float* __restrict__ escal, const int* __restrict__ csr2edge,
    const float* __restrict__ Wfc1, const float* __restrict__ Wfc2,
    _Float16* __restrict__ w_s, int E)
{
    __shared__ _Float16 sW2T[128 * 128];   // 32 KB, [col][k] swizzled
    __shared__ _Float16 sH[8][16 * 128];   // 4 KB per wave (h, then w staging)

    const int tid = threadIdx.x;
    const int wid = tid >> 6;              // wave 0..7
    const int l   = tid & 63;
    const int c16 = l & 15;
    const int kq  = l >> 4;

    _Float16* Hw = sH[wid];

    {
        int* z2 = (int*)sW2T;
        for (int i = tid; i < 128 * 128 / 2; i += 512) z2[i] = 0;
    }
    __syncthreads();
    for (int i = tid; i < 100 * 128; i += 512) {
        const int k = i >> 7, col = i & 127;
        sW2T[col * 128 + (k ^ ((col & 7) << 3))] = (_Float16)Wfc2[i];
    }

    f16x8 bW1[7];
#pragma unroll
    for (int cb = 0; cb < 7; ++cb) {
        const int col = cb * 16 + c16;
#pragma unroll
        for (int j = 0; j < 8; ++j) {
            const int k = kq * 8 + j;
            bW1[cb][j] = (k < 10 && col < 100) ? (_Float16)Wfc1[k * 100 + col]
                                               : (_Float16)0.f;
        }
    }
#pragma unroll
    for (int r = 0; r < 4; ++r) {
        const int row = kq * 4 + r;
        const int col = 112 + c16;
        Hw[row * 128 + (col ^ ((row & 7) << 3))] = (_Float16)0.f;
    }
    __syncthreads();   // W2T visible to all waves; no barriers after this

    const float inv_s10 = 0.31622776601683794f; // 1/sqrt(10)

    const int gw = blockIdx.x * 8 + wid;
    const int nw = gridDim.x * 8;
    const int step = nw * 16;

    int base = gw * 16;
    f16x8 a1;
    {
        const int ge = base + c16;
        const int ee = (ge < E) ? csr2edge[ge] : 0;
#pragma unroll
        for (int j = 0; j < 8; ++j) {
            const int k = kq * 8 + j;
            a1[j] = (k < 10 && ge < E) ? (_Float16)escal[(size_t)ee * 10 + k]
                                       : (_Float16)0.f;
        }
    }

    for (; base < E; base += step) {
#pragma unroll
        for (int cb = 0; cb < 7; ++cb) {
            f32x4 z = {0.f, 0.f, 0.f, 0.f};
            z = __builtin_amdgcn_mfma_f32_16x16x32_f16(a1, bW1[cb], z, 0, 0, 0);
#pragma unroll
            for (int r = 0; r < 4; ++r) {
                const int row = kq * 4 + r;
                const int col = cb * 16 + c16;
                const float h = silu_f(z[r] * inv_s10) * 0.1f;
                Hw[row * 128 + (col ^ ((row & 7) << 3))] = (_Float16)h;
            }
        }

        f16x8 a1n;
        {
            const int ge = base + step + c16;
            const int ee = (ge < E) ? csr2edge[ge] : 0;
#pragma unroll
            for (int j = 0; j < 8; ++j) {
                const int k = kq * 8 + j;
                a1n[j] = (k < 10 && ge < E)
                         ? (_Float16)escal[(size_t)ee * 10 + k]
                         : (_Float16)0.f;
            }
        }

        f32x4 acc0 = {0.f,0.f,0.f,0.f}, acc1 = {0.f,0.f,0.f,0.f};
        f32x4 acc2 = {0.f,0.f,0.f,0.f}, acc3 = {0.f,0.f,0.f,0.f};
        f32x4 acc4 = {0.f,0.f,0.f,0.f}, acc5 = {0.f,0.f,0.f,0.f};
        f32x4 acc6 = {0.f,0.f,0.f,0.f}, acc7 = {0.f,0.f,0.f,0.f};
#pragma unroll
        for (int kk = 0; kk < 4; ++kk) {
            const f16x8 a2 = *(const f16x8*)&Hw[c16 * 128 +
                                ((kk * 32 + kq * 8) ^ ((c16 & 7) << 3))];
#define BFRAG(CB) (*(const f16x8*)&sW2T[((CB) * 16 + c16) * 128 + \
                       ((kk * 32 + kq * 8) ^ ((c16 & 7) << 3))])
            acc0 = __builtin_amdgcn_mfma_f32_16x16x32_f16(a2, BFRAG(0), acc0, 0, 0, 0);
            acc1 = __builtin_amdgcn_mfma_f32_16x16x32_f16(a2, BFRAG(1), acc1, 0, 0, 0);
            acc2 = __builtin_amdgcn_mfma_f32_16x16x32_f16(a2, BFRAG(2), acc2, 0, 0, 0);
            acc3 = __builtin_amdgcn_mfma_f32_16x16x32_f16(a2, BFRAG(3), acc3, 0, 0, 0);
            acc4 = __builtin_amdgcn_mfma_f32_16x16x32_f16(a2, BFRAG(4), acc4, 0, 0, 0);
            acc5 = __builtin_amdgcn_mfma_f32_16x16x32_f16(a2, BFRAG(5), acc5, 0, 0, 0);
            acc6 = __builtin_amdgcn_mfma_f32_16x16x32_f16(a2, BFRAG(6), acc6, 0, 0, 0);
            acc7 = __builtin_amdgcn_mfma_f32_16x16x32_f16(a2, BFRAG(7), acc7, 0, 0, 0);
#undef BFRAG
        }

#define STAGE_CB(CB, ACC)                                                     \
        {                                                                     \
            _Pragma("unroll")                                                 \
            for (int r = 0; r < 4; ++r) {                                     \
                const int row = kq * 4 + r;                                   \
                const int col = (CB) * 16 + c16;                              \
                Hw[row * 128 + (col ^ ((row & 7) << 3))] = (_Float16)(ACC)[r];\
            }                                                                 \
        }
        STAGE_CB(0, acc0) STAGE_CB(1, acc1) STAGE_CB(2, acc2) STAGE_CB(3, acc3)
        STAGE_CB(4, acc4) STAGE_CB(5, acc5) STAGE_CB(6, acc6) STAGE_CB(7, acc7)
#undef STAGE_CB

#pragma unroll
        for (int i = 0; i < 4; ++i) {
            const int e = i * 4 + (l >> 4);
            const int colb = (l & 15) * 8;
            const f16x8 v = *(const f16x8*)&Hw[e * 128 +
                                (colb ^ ((e & 7) << 3))];
            if (base + e < E)
                *(f16x8*)&w_s[(size_t)(base + e) * 128 + colb] = v;
        }

        a1 = a1n;
    }
}

// ---------------------------------------------------------------------------
// Kernel C: gather + mean + fused post. Sequential w reads; 4-deep
// straight-line edge unroll (plain scalars, no arrays -> no spill).
// ---------------------------------------------------------------------------
__global__ __launch_bounds__(256) void gather_post_kernel(
    const _Float16* __restrict__ w_s, const int* __restrict__ src_s,
    const float4* __restrict__ sh_s, const int* __restrict__ row_ptr,
    const _Float16* __restrict__ y, const float* __restrict__ attr,
    const float* __restrict__ Wl20, const float* __restrict__ Wl21,
    const float* __restrict__ Walpha,
    float* __restrict__ out, int N)
{
    __shared__ float sW0[64 * 32];
    __shared__ float sW1[64 * 32];
    __shared__ float sWa[64];
    __shared__ float sMid[4][256];   // per-wave: [mid0(64) | midT(3x64)]

    const int tid = threadIdx.x;
    for (int i = tid; i < 64 * 32; i += 256) {
        sW0[i] = Wl20[i];
        sW1[i] = Wl21[i];
    }
    if (tid < 64) sWa[tid] = Walpha[tid];
    __syncthreads();   // only barrier; node loop is barrier-free

    const int wid = tid >> 6;
    const int L   = tid & 63;
    const bool hi = (L >= 32);
    const int u   = L & 31;

    const int wAi = hi ? 32 + u : u;
    const int wBi = hi ? 96 + u : 64 + u;
    const int yi0 = hi ? 32 + 3 * u + 0 : u;
    const int yi1 = hi ? 32 + 3 * u + 1 : u;
    const int yi2 = hi ? 32 + 3 * u + 2 : u;
    const float mulA = hi ? 0.5773502691896258f : 1.0f;   // 1/sqrt(3) on m11

    const int o1m = L - 32;
    const int v1 = hi ? o1m / 3 : 0;
    const int c1 = hi ? o1m - v1 * 3 : 0;
    const int o2m = L + 32;
    const int v2 = o2m / 3;
    const int c2 = o2m - v2 * 3;
    const float* wcol1 = hi ? (sW1 + v1) : (sW0 + L);
    const float* wcol2 = sW1 + v2;

    float* midw = &sMid[wid][0];
    const float* msrc1c = hi ? (midw + 64 + c1 * 64) : midw;
    const float* msrc2c = midw + 64 + c2 * 64;

#define LOAD_EDGE(J, SH, WA, WB, Q0, Q1, Q2) \
        const int s_##J = src_s[(J)];                                  \
        const float4 SH = sh_s[(J)];                                   \
        const _Float16* wr_##J = w_s + (size_t)(J) * 128;              \
        const _Float16* yr_##J = y + (size_t)s_##J * 128;              \
        const float WA = (float)wr_##J[wAi], WB = (float)wr_##J[wBi];  \
        const float Q0 = (float)yr_##J[yi0];                           \
        const float Q1 = (float)yr_##J[yi1];                           \
        const float Q2 = (float)yr_##J[yi2];

#define ACC_EDGE(sh, wAv, wBv, q0, q1, q2) do {                        \
        const float sA0 = hi ? (sh).y : (sh).x;                        \
        const float sA1 = hi ? (sh).z : 0.f;                           \
        const float sA2 = hi ? (sh).w : 0.f;                           \
        const float b1s = hi ? (sh).x : (sh).y;                        \
        const float b2s = hi ? (sh).x : (sh).z;                        \
        const float b3s = hi ? (sh).x : (sh).w;                        \
        accA += (wAv) * mulA * ((q0) * sA0 + (q1) * sA1 + (q2) * sA2); \
        acc1 += (wBv) * (q0) * b1s;                                    \
        acc2 += (wBv) * (q1) * b2s;                                    \
        acc3 += (wBv) * (q2) * b3s;                                    \
    } while (0)

    const int waves_glob = gridDim.x * 4;
    for (int n = blockIdx.x * 4 + wid; n < N; n += waves_glob) {
        const int jlo = row_ptr[n];
        const int jhi = row_ptr[n + 1];
        const int deg = jhi - jlo;
        if (deg <= 0) continue;

        float accA = 0.f, acc1 = 0.f, acc2 = 0.f, acc3 = 0.f;

        int j = jlo;
        for (; j + 4 <= jhi; j += 4) {
            LOAD_EDGE(j,     shA, wAa, wBa, qa0, qa1, qa2)
            const int jb = j + 1;
            LOAD_EDGE(jb,    shB, wAb, wBb, qb0, qb1, qb2)
            const int jc = j + 2;
            LOAD_EDGE(jc,    shC, wAc, wBc, qc0, qc1, qc2)
            const int jd = j + 3;
            LOAD_EDGE(jd,    shD, wAd, wBd, qd0, qd1, qd2)
            ACC_EDGE(shA, wAa, wBa, qa0, qa1, qa2);
            ACC_EDGE(shB, wAb, wBb, qb0, qb1, qb2);
            ACC_EDGE(shC, wAc, wBc, qc0, qc1, qc2);
            ACC_EDGE(shD, wAd, wBd, qd0, qd1, qd2);
        }
        for (; j < jhi; ++j) {
            LOAD_EDGE(j, shA, wAa, wBa, qa0, qa1, qa2)
            ACC_EDGE(shA, wAa, wBa, qa0, qa1, qa2);
        }

        const float rdeg = 1.0f / (float)deg;
        const float a = attr[n];

        float term = accA * rdeg * sWa[L];
#pragma unroll
        for (int off = 32; off; off >>= 1) term += __shfl_xor(term, off);
        const float alpha = term * 0.125f * a;

        midw[L]            = accA * rdeg;
        midw[64 + L]       = acc1 * rdeg;
        midw[128 + L]      = acc2 * rdeg;
        midw[192 + L]      = acc3 * rdeg;

        float cv1 = 0.f, cv2 = 0.f;
#pragma unroll
        for (int kk = 0; kk < 16; ++kk) {
            const float4 m1 = *(const float4*)&msrc1c[4 * kk];
            const float4 m2 = *(const float4*)&msrc2c[4 * kk];
            cv1 += m1.x * wcol1[(4 * kk + 0) * 32] + m1.y * wcol1[(4 * kk + 1) * 32]
                 + m1.z * wcol1[(4 * kk + 2) * 32] + m1.w * wcol1[(4 * kk + 3) * 32];
            cv2 += m2.x * wcol2[(4 * kk + 0) * 32] + m2.y * wcol2[(4 * kk + 1) * 32]
                 + m2.z * wcol2[(4 * kk + 2) * 32] + m2.w * wcol2[(4 * kk + 3) * 32];
        }
        const float f = alpha * 0.125f * a;
        const size_t ob = (size_t)n * 128;
        out[ob + L]      += f * cv1;
        out[ob + 64 + L] += f * cv2;
    }
#undef ACC_EDGE
#undef LOAD_EDGE
}

extern "C" void kernel_launch(void* const* d_in, const int* in_sizes, int n_in,
                              void* d_out, int out_size, void* d_ws, size_t ws_size,
                              hipStream_t stream)
{
    const float* x      = (const float*)d_in[0];
    const float* attr   = (const float*)d_in[1];
    const int*   esrc   = (const int*)  d_in[2];
    const int*   edst   = (const int*)  d_in[3];
    const float* esh    = (const float*)d_in[4];
    const float* escal  = (const float*)d_in[5];
    const float* Wfc1   = (const float*)d_in[6];
    const float* Wfc2   = (const float*)d_in[7];
    const float* Wsc0   = (const float*)d_in[8];
    const float* Wsc1   = (const float*)d_in[9];
    const float* Wl10   = (const float*)d_in[10];
    const float* Wl11   = (const float*)d_in[11];
    const float* Wl20   = (const float*)d_in[12];
    const float* Wl21   = (const float*)d_in[13];
    const float* Walpha = (const float*)d_in[14];

    const int N = in_sizes[1];
    const int E = in_sizes[2];
    float* out = (float*)d_out;

    // ws: y(f16) | row_ptr | deg | cur | bsum | boff | csr2edge | src_s |
    //     [align16] sh_s | w_s
    char* p = (char*)d_ws;
    _Float16* y   = (_Float16*)p; p += (size_t)N * 128 * sizeof(_Float16);
    int* row_ptr  = (int*)p;      p += (size_t)(N + 1) * sizeof(int);
    int* deg      = (int*)p;      p += (size_t)N * sizeof(int);
    int* cur      = (int*)p;      p += (size_t)N * sizeof(int);
    int* bsum     = (int*)p;      p += 256 * sizeof(int);
    int* boff     = (int*)p;      p += 256 * sizeof(int);
    int* csr2edge = (int*)p;      p += (size_t)E * sizeof(int);
    int* src_s    = (int*)p;      p += (size_t)E * sizeof(int);
    p = (char*)(((uintptr_t)p + 15) & ~(uintptr_t)15);
    float4* sh_s  = (float4*)p;   p += (size_t)E * sizeof(float4);
    _Float16* w_s = (_Float16*)p;

    const int NB = (N + SCAN_CH) / SCAN_CH;   // covers row_ptr[N]

    hipMemsetAsync(deg, 0, (size_t)2 * N * sizeof(int), stream);

    node_pre_kernel<<<1024, 256, 0, stream>>>(x, attr, Wsc0, Wsc1, Wl10, Wl11,
                                              out, y, N);
    hist_kernel<<<512, 256, 0, stream>>>(edst, deg, E);
    scanA_kernel<<<NB, 256, 0, stream>>>(deg, bsum, N);
    scanB_kernel<<<1, 256, 0, stream>>>(bsum, boff, NB);
    scanC_kernel<<<NB, 256, 0, stream>>>(deg, boff, row_ptr, N);
    fill_kernel<<<512, 256, 0, stream>>>(esrc, edst, esh, row_ptr, cur,
                                         csr2edge, src_s, sh_s, E);
    edge_w_kernel<<<512, 512, 0, stream>>>(escal, csr2edge, Wfc1, Wfc2, w_s, E);
    gather_post_kernel<<<4096, 256, 0, stream>>>(w_s, src_s, sh_s, row_ptr,
                                                 y, attr, Wl20, Wl21, Walpha,
                                                 out, N);
}

// Round 20
// 236.990 us; speedup vs baseline: 1.6181x; 1.0661x over previous
//
#include <hip/hip_runtime.h>
#include <hip/hip_bf16.h>

#define MUL 32
#define SCAN_CH 1024

typedef _Float16 f16x8 __attribute__((ext_vector_type(8)));
typedef float f32x4 __attribute__((ext_vector_type(4)));

static __device__ __forceinline__ float silu_f(float z) {
    return z / (1.0f + __expf(-z));
}

// ---------------------------------------------------------------------------
// Kernel A: per-node pre-pass, wave-per-node, barrier-free. (r14-r17 verified)
// ---------------------------------------------------------------------------
__global__ __launch_bounds__(256) void node_pre_kernel(
    const float* __restrict__ x, const float* __restrict__ attr,
    const float* __restrict__ Wsc0, const float* __restrict__ Wsc1,
    const float* __restrict__ Wl10, const float* __restrict__ Wl11,
    float* __restrict__ sc_out, _Float16* __restrict__ y_out, int N)
{
    __shared__ float sX[4][128];
    const int tid = threadIdx.x;
    const int wid = tid >> 6, L = tid & 63;
    float* xs = sX[wid];
    const float inv = 0.17677669529663687f; // 1/sqrt(32)

    const bool t0 = (L < 32);
    const int i1 = t0 ? 0 : (L - 32);
    const int v1 = i1 / 3, c1 = i1 - v1 * 3;
    const int i2 = L + 32;
    const int v2 = i2 / 3, c2 = i2 - v2 * 3;

    const int xb1 = t0 ? 0 : (32 + c1);
    const int xst1 = t0 ? 1 : 3;

    float wA[32], wB[32], wC[32], wD[32];
#pragma unroll
    for (int u = 0; u < 32; ++u) {
        wA[u] = t0 ? Wsc0[u * 32 + L] : Wsc1[u * 32 + v1];
        wB[u] = t0 ? Wl10[u * 32 + L] : Wl11[u * 32 + v1];
        wC[u] = Wsc1[u * 32 + v2];
        wD[u] = Wl11[u * 32 + v2];
    }

    const int stride = gridDim.x * 4;
    for (int n = blockIdx.x * 4 + wid; n < N; n += stride) {
        xs[L]      = x[(size_t)n * 128 + L];
        xs[64 + L] = x[(size_t)n * 128 + 64 + L];
        const float scale = inv * attr[n];
        float a0 = 0.f, a1 = 0.f, b0 = 0.f, b1 = 0.f;
#pragma unroll
        for (int u = 0; u < 32; ++u) {
            const float xv1 = xs[xb1 + u * xst1];
            const float xv2 = xs[32 + u * 3 + c2];
            a0 += xv1 * wA[u];
            a1 += xv1 * wB[u];
            b0 += xv2 * wC[u];
            b1 += xv2 * wD[u];
        }
        sc_out[(size_t)n * 128 + L]      = a0 * scale;
        sc_out[(size_t)n * 128 + 64 + L] = b0 * scale;
        y_out [(size_t)n * 128 + L]      = (_Float16)(a1 * scale);
        y_out [(size_t)n * 128 + 64 + L] = (_Float16)(b1 * scale);
    }
}

// ---------------------------------------------------------------------------
// CSR build: histogram -> 3-phase coalesced scan -> fill. (r17-verified)
// ---------------------------------------------------------------------------
__global__ void hist_kernel(const int* __restrict__ edst, int* __restrict__ deg, int E)
{
    int i = blockIdx.x * blockDim.x + threadIdx.x;
    const int stride = gridDim.x * blockDim.x;
    for (; i < E; i += stride) atomicAdd(&deg[edst[i]], 1);
}

__global__ __launch_bounds__(256) void scanA_kernel(
    const int* __restrict__ deg, int* __restrict__ bsum, int N)
{
    __shared__ int red[256];
    const int t = threadIdx.x, b = blockIdx.x;
    const int base = b * SCAN_CH;
    int s = 0;
#pragma unroll
    for (int k = 0; k < 4; ++k) {
        const int idx = base + t + k * 256;
        if (idx < N) s += deg[idx];
    }
    red[t] = s;
    __syncthreads();
    for (int off = 128; off; off >>= 1) {
        if (t < off) red[t] += red[t + off];
        __syncthreads();
    }
    if (t == 0) bsum[b] = red[0];
}

__global__ __launch_bounds__(256) void scanB_kernel(
    const int* __restrict__ bsum, int* __restrict__ boff, int NB)
{
    __shared__ int s[256];
    const int t = threadIdx.x;
    const int v = (t < NB) ? bsum[t] : 0;
    s[t] = v;
    __syncthreads();
    for (int off = 1; off < 256; off <<= 1) {
        const int add = (t >= off) ? s[t - off] : 0;
        __syncthreads();
        s[t] += add;
        __syncthreads();
    }
    if (t < NB) boff[t] = s[t] - v;
}

__global__ __launch_bounds__(256) void scanC_kernel(
    const int* __restrict__ deg, const int* __restrict__ boff,
    int* __restrict__ row_ptr, int N)
{
    __shared__ int ts[256];
    const int t = threadIdx.x, b = blockIdx.x;
    const int base = b * SCAN_CH + t * 4;
    int d0 = 0, d1 = 0, d2 = 0, d3 = 0;
    if (base + 0 < N) d0 = deg[base + 0];
    if (base + 1 < N) d1 = deg[base + 1];
    if (base + 2 < N) d2 = deg[base + 2];
    if (base + 3 < N) d3 = deg[base + 3];
    const int tsum = d0 + d1 + d2 + d3;
    ts[t] = tsum;
    __syncthreads();
    for (int off = 1; off < 256; off <<= 1) {
        const int add = (t >= off) ? ts[t - off] : 0;
        __syncthreads();
        ts[t] += add;
        __syncthreads();
    }
    int run = boff[b] + ts[t] - tsum;
    if (base + 0 <= N) row_ptr[base + 0] = run;
    run += d0;
    if (base + 1 <= N) row_ptr[base + 1] = run;
    run += d1;
    if (base + 2 <= N) row_ptr[base + 2] = run;
    run += d2;
    if (base + 3 <= N) row_ptr[base + 3] = run;
}

__global__ void fill_kernel(
    const int* __restrict__ esrc, const int* __restrict__ edst,
    const float* __restrict__ esh,
    const int* __restrict__ row_ptr, int* __restrict__ cur,
    int* __restrict__ csr2edge, int* __restrict__ src_s, float4* __restrict__ sh_s,
    int E)
{
    int i = blockIdx.x * blockDim.x + threadIdx.x;
    const int stride = gridDim.x * blockDim.x;
    for (; i < E; i += stride) {
        const int d = edst[i];
        const int p = row_ptr[d] + atomicAdd(&cur[d], 1);
        csr2edge[p] = i;
        src_s[p] = esrc[i];
        sh_s[p] = *(const float4*)&esh[(size_t)i * 4];
    }
}

// ---------------------------------------------------------------------------
// Kernel B: edge MLP -> w (f16, CSR-slot order, sequential stores). (r17,
// 88 us verified: 512 threads, 8 waves share W2T, 2 blocks/CU, grid 512)
// ---------------------------------------------------------------------------
__global__ __launch_bounds__(512) void edge_w_kernel(
    const float* __restrict__ escal, const int* __restrict__ csr2edge,
    const float* __restrict__ Wfc1, const float* __restrict__ Wfc2,
    _Float16* __restrict__ w_s, int E)
{
    __shared__ _Float16 sW2T[128 * 128];   // 32 KB, [col][k] swizzled
    __shared__ _Float16 sH[8][16 * 128];   // 4 KB per wave (h, then w staging)

    const int tid = threadIdx.x;
    const int wid = tid >> 6;              // wave 0..7
    const int l   = tid & 63;
    const int c16 = l & 15;
    const int kq  = l >> 4;

    _Float16* Hw = sH[wid];

    {
        int* z2 = (int*)sW2T;
        for (int i = tid; i < 128 * 128 / 2; i += 512) z2[i] = 0;
    }
    __syncthreads();
    for (int i = tid; i < 100 * 128; i += 512) {
        const int k = i >> 7, col = i & 127;
        sW2T[col * 128 + (k ^ ((col & 7) << 3))] = (_Float16)Wfc2[i];
    }

    f16x8 bW1[7];
#pragma unroll
    for (int cb = 0; cb < 7; ++cb) {
        const int col = cb * 16 + c16;
#pragma unroll
        for (int j = 0; j < 8; ++j) {
            const int k = kq * 8 + j;
            bW1[cb][j] = (k < 10 && col < 100) ? (_Float16)Wfc1[k * 100 + col]
                                               : (_Float16)0.f;
        }
    }
#pragma unroll
    for (int r = 0; r < 4; ++r) {
        const int row = kq * 4 + r;
        const int col = 112 + c16;
        Hw[row * 128 + (col ^ ((row & 7) << 3))] = (_Float16)0.f;
    }
    __syncthreads();   // W2T visible to all waves; no barriers after this

    const float inv_s10 = 0.31622776601683794f; // 1/sqrt(10)

    const int gw = blockIdx.x * 8 + wid;
    const int nw = gridDim.x * 8;
    const int step = nw * 16;

    int base = gw * 16;
    f16x8 a1;
    {
        const int ge = base + c16;
        const int ee = (ge < E) ? csr2edge[ge] : 0;
#pragma unroll
        for (int j = 0; j < 8; ++j) {
            const int k = kq * 8 + j;
            a1[j] = (k < 10 && ge < E) ? (_Float16)escal[(size_t)ee * 10 + k]
                                       : (_Float16)0.f;
        }
    }

    for (; base < E; base += step) {
#pragma unroll
        for (int cb = 0; cb < 7; ++cb) {
            f32x4 z = {0.f, 0.f, 0.f, 0.f};
            z = __builtin_amdgcn_mfma_f32_16x16x32_f16(a1, bW1[cb], z, 0, 0, 0);
#pragma unroll
            for (int r = 0; r < 4; ++r) {
                const int row = kq * 4 + r;
                const int col = cb * 16 + c16;
                const float h = silu_f(z[r] * inv_s10) * 0.1f;
                Hw[row * 128 + (col ^ ((row & 7) << 3))] = (_Float16)h;
            }
        }

        f16x8 a1n;
        {
            const int ge = base + step + c16;
            const int ee = (ge < E) ? csr2edge[ge] : 0;
#pragma unroll
            for (int j = 0; j < 8; ++j) {
                const int k = kq * 8 + j;
                a1n[j] = (k < 10 && ge < E)
                         ? (_Float16)escal[(size_t)ee * 10 + k]
                         : (_Float16)0.f;
            }
        }

        f32x4 acc0 = {0.f,0.f,0.f,0.f}, acc1 = {0.f,0.f,0.f,0.f};
        f32x4 acc2 = {0.f,0.f,0.f,0.f}, acc3 = {0.f,0.f,0.f,0.f};
        f32x4 acc4 = {0.f,0.f,0.f,0.f}, acc5 = {0.f,0.f,0.f,0.f};
        f32x4 acc6 = {0.f,0.f,0.f,0.f}, acc7 = {0.f,0.f,0.f,0.f};
#pragma unroll
        for (int kk = 0; kk < 4; ++kk) {
            const f16x8 a2 = *(const f16x8*)&Hw[c16 * 128 +
                                ((kk * 32 + kq * 8) ^ ((c16 & 7) << 3))];
#define BFRAG(CB) (*(const f16x8*)&sW2T[((CB) * 16 + c16) * 128 + \
                       ((kk * 32 + kq * 8) ^ ((c16 & 7) << 3))])
            acc0 = __builtin_amdgcn_mfma_f32_16x16x32_f16(a2, BFRAG(0), acc0, 0, 0, 0);
            acc1 = __builtin_amdgcn_mfma_f32_16x16x32_f16(a2, BFRAG(1), acc1, 0, 0, 0);
            acc2 = __builtin_amdgcn_mfma_f32_16x16x32_f16(a2, BFRAG(2), acc2, 0, 0, 0);
            acc3 = __builtin_amdgcn_mfma_f32_16x16x32_f16(a2, BFRAG(3), acc3, 0, 0, 0);
            acc4 = __builtin_amdgcn_mfma_f32_16x16x32_f16(a2, BFRAG(4), acc4, 0, 0, 0);
            acc5 = __builtin_amdgcn_mfma_f32_16x16x32_f16(a2, BFRAG(5), acc5, 0, 0, 0);
            acc6 = __builtin_amdgcn_mfma_f32_16x16x32_f16(a2, BFRAG(6), acc6, 0, 0, 0);
            acc7 = __builtin_amdgcn_mfma_f32_16x16x32_f16(a2, BFRAG(7), acc7, 0, 0, 0);
#undef BFRAG
        }

#define STAGE_CB(CB, ACC)                                                     \
        {                                                                     \
            _Pragma("unroll")                                                 \
            for (int r = 0; r < 4; ++r) {                                     \
                const int row = kq * 4 + r;                                   \
                const int col = (CB) * 16 + c16;                              \
                Hw[row * 128 + (col ^ ((row & 7) << 3))] = (_Float16)(ACC)[r];\
            }                                                                 \
        }
        STAGE_CB(0, acc0) STAGE_CB(1, acc1) STAGE_CB(2, acc2) STAGE_CB(3, acc3)
        STAGE_CB(4, acc4) STAGE_CB(5, acc5) STAGE_CB(6, acc6) STAGE_CB(7, acc7)
#undef STAGE_CB

#pragma unroll
        for (int i = 0; i < 4; ++i) {
            const int e = i * 4 + (l >> 4);
            const int colb = (l & 15) * 8;
            const f16x8 v = *(const f16x8*)&Hw[e * 128 +
                                (colb ^ ((e & 7) << 3))];
            if (base + e < E)
                *(f16x8*)&w_s[(size_t)(base + e) * 128 + colb] = v;
        }

        a1 = a1n;
    }
}

// ---------------------------------------------------------------------------
// Kernel C: gather + mean + fused post. r17 2-deep edge loop restored;
// epilogue now uses TRANSPOSED padded weights ([o][u], pad 68 -> 16B-aligned
// rows): 16 ds_read_b128 per output instead of 64 strided ds_read_b32.
// ---------------------------------------------------------------------------
__global__ __launch_bounds__(256) void gather_post_kernel(
    const _Float16* __restrict__ w_s, const int* __restrict__ src_s,
    const float4* __restrict__ sh_s, const int* __restrict__ row_ptr,
    const _Float16* __restrict__ y, const float* __restrict__ attr,
    const float* __restrict__ Wl20, const float* __restrict__ Wl21,
    const float* __restrict__ Walpha,
    float* __restrict__ out, int N)
{
    __shared__ float sW0T[32 * 68];   // [o][u] padded, 8.7 KB
    __shared__ float sW1T[32 * 68];   // [o][u] padded, 8.7 KB
    __shared__ float sWa[64];
    __shared__ float sMid[4][256];    // per-wave: [mid0(64) | midT(3x64)]

    const int tid = threadIdx.x;
    for (int i = tid; i < 64 * 32; i += 256) {
        const int u = i >> 5, o = i & 31;
        sW0T[o * 68 + u] = Wl20[i];
        sW1T[o * 68 + u] = Wl21[i];
    }
    if (tid < 64) sWa[tid] = Walpha[tid];
    __syncthreads();   // only barrier; node loop is barrier-free

    const int wid = tid >> 6;
    const int L   = tid & 63;
    const bool hi = (L >= 32);
    const int u   = L & 31;

    const int wAi = hi ? 32 + u : u;
    const int wBi = hi ? 96 + u : 64 + u;
    const int yi0 = hi ? 32 + 3 * u + 0 : u;
    const int yi1 = hi ? 32 + 3 * u + 1 : u;
    const int yi2 = hi ? 32 + 3 * u + 2 : u;
    const float mulA = hi ? 0.5773502691896258f : 1.0f;   // 1/sqrt(3) on m11

    const int o1m = L - 32;
    const int v1 = hi ? o1m / 3 : 0;
    const int c1 = hi ? o1m - v1 * 3 : 0;
    const int o2m = L + 32;
    const int v2 = o2m / 3;
    const int c2 = o2m - v2 * 3;
    const float* wrow1 = hi ? (sW1T + v1 * 68) : (sW0T + L * 68);
    const float* wrow2 = sW1T + v2 * 68;

    float* midw = &sMid[wid][0];
    const float* msrc1c = hi ? (midw + 64 + c1 * 64) : midw;
    const float* msrc2c = midw + 64 + c2 * 64;

#define ACC_EDGE(sh, wAv, wBv, q0, q1, q2) do {                        \
        const float sA0 = hi ? (sh).y : (sh).x;                        \
        const float sA1 = hi ? (sh).z : 0.f;                           \
        const float sA2 = hi ? (sh).w : 0.f;                           \
        const float b1s = hi ? (sh).x : (sh).y;                        \
        const float b2s = hi ? (sh).x : (sh).z;                        \
        const float b3s = hi ? (sh).x : (sh).w;                        \
        accA += (wAv) * mulA * ((q0) * sA0 + (q1) * sA1 + (q2) * sA2); \
        acc1 += (wBv) * (q0) * b1s;                                    \
        acc2 += (wBv) * (q1) * b2s;                                    \
        acc3 += (wBv) * (q2) * b3s;                                    \
    } while (0)

    const int waves_glob = gridDim.x * 4;
    for (int n = blockIdx.x * 4 + wid; n < N; n += waves_glob) {
        const int jlo = row_ptr[n];
        const int jhi = row_ptr[n + 1];
        const int deg = jhi - jlo;
        if (deg <= 0) continue;

        float accA = 0.f, acc1 = 0.f, acc2 = 0.f, acc3 = 0.f;

        int j = jlo;
        for (; j + 2 <= jhi; j += 2) {
            const int sa = src_s[j];
            const int sb = src_s[j + 1];
            const float4 shA = sh_s[j];
            const float4 shB = sh_s[j + 1];
            const _Float16* wra = w_s + (size_t)j * 128;
            const _Float16* wrb = wra + 128;
            const _Float16* yra = y + (size_t)sa * 128;
            const _Float16* yrb = y + (size_t)sb * 128;
            const float wAa = (float)wra[wAi], wBa = (float)wra[wBi];
            const float qa0 = (float)yra[yi0], qa1 = (float)yra[yi1], qa2 = (float)yra[yi2];
            const float wAb = (float)wrb[wAi], wBb = (float)wrb[wBi];
            const float qb0 = (float)yrb[yi0], qb1 = (float)yrb[yi1], qb2 = (float)yrb[yi2];
            ACC_EDGE(shA, wAa, wBa, qa0, qa1, qa2);
            ACC_EDGE(shB, wAb, wBb, qb0, qb1, qb2);
        }
        if (j < jhi) {
            const int sa = src_s[j];
            const float4 shA = sh_s[j];
            const _Float16* wra = w_s + (size_t)j * 128;
            const _Float16* yra = y + (size_t)sa * 128;
            const float wAa = (float)wra[wAi], wBa = (float)wra[wBi];
            const float qa0 = (float)yra[yi0], qa1 = (float)yra[yi1], qa2 = (float)yra[yi2];
            ACC_EDGE(shA, wAa, wBa, qa0, qa1, qa2);
        }

        const float rdeg = 1.0f / (float)deg;
        const float a = attr[n];

        float term = accA * rdeg * sWa[L];
#pragma unroll
        for (int off = 32; off; off >>= 1) term += __shfl_xor(term, off);
        const float alpha = term * 0.125f * a;

        midw[L]            = accA * rdeg;
        midw[64 + L]       = acc1 * rdeg;
        midw[128 + L]      = acc2 * rdeg;
        midw[192 + L]      = acc3 * rdeg;

        float cv1 = 0.f, cv2 = 0.f;
#pragma unroll
        for (int kk = 0; kk < 16; ++kk) {
            const float4 m1 = *(const float4*)&msrc1c[4 * kk];
            const float4 m2 = *(const float4*)&msrc2c[4 * kk];
            const float4 w1 = *(const float4*)&wrow1[4 * kk];
            const float4 w2 = *(const float4*)&wrow2[4 * kk];
            cv1 += m1.x * w1.x + m1.y * w1.y + m1.z * w1.z + m1.w * w1.w;
            cv2 += m2.x * w2.x + m2.y * w2.y + m2.z * w2.z + m2.w * w2.w;
        }
        const float f = alpha * 0.125f * a;
        const size_t ob = (size_t)n * 128;
        out[ob + L]      += f * cv1;
        out[ob + 64 + L] += f * cv2;
    }
#undef ACC_EDGE
}

extern "C" void kernel_launch(void* const* d_in, const int* in_sizes, int n_in,
                              void* d_out, int out_size, void* d_ws, size_t ws_size,
                              hipStream_t stream)
{
    const float* x      = (const float*)d_in[0];
    const float* attr   = (const float*)d_in[1];
    const int*   esrc   = (const int*)  d_in[2];
    const int*   edst   = (const int*)  d_in[3];
    const float* esh    = (const float*)d_in[4];
    const float* escal  = (const float*)d_in[5];
    const float* Wfc1   = (const float*)d_in[6];
    const float* Wfc2   = (const float*)d_in[7];
    const float* Wsc0   = (const float*)d_in[8];
    const float* Wsc1   = (const float*)d_in[9];
    const float* Wl10   = (const float*)d_in[10];
    const float* Wl11   = (const float*)d_in[11];
    const float* Wl20   = (const float*)d_in[12];
    const float* Wl21   = (const float*)d_in[13];
    const float* Walpha = (const float*)d_in[14];

    const int N = in_sizes[1];
    const int E = in_sizes[2];
    float* out = (float*)d_out;

    // ws: y(f16) | row_ptr | deg | cur | bsum | boff | csr2edge | src_s |
    //     [align16] sh_s | w_s
    char* p = (char*)d_ws;
    _Float16* y   = (_Float16*)p; p += (size_t)N * 128 * sizeof(_Float16);
    int* row_ptr  = (int*)p;      p += (size_t)(N + 1) * sizeof(int);
    int* deg      = (int*)p;      p += (size_t)N * sizeof(int);
    int* cur      = (int*)p;      p += (size_t)N * sizeof(int);
    int* bsum     = (int*)p;      p += 256 * sizeof(int);
    int* boff     = (int*)p;      p += 256 * sizeof(int);
    int* csr2edge = (int*)p;      p += (size_t)E * sizeof(int);
    int* src_s    = (int*)p;      p += (size_t)E * sizeof(int);
    p = (char*)(((uintptr_t)p + 15) & ~(uintptr_t)15);
    float4* sh_s  = (float4*)p;   p += (size_t)E * sizeof(float4);
    _Float16* w_s = (_Float16*)p;

    const int NB = (N + SCAN_CH) / SCAN_CH;   // covers row_ptr[N]

    hipMemsetAsync(deg, 0, (size_t)2 * N * sizeof(int), stream);

    node_pre_kernel<<<1024, 256, 0, stream>>>(x, attr, Wsc0, Wsc1, Wl10, Wl11,
                                              out, y, N);
    hist_kernel<<<512, 256, 0, stream>>>(edst, deg, E);
    scanA_kernel<<<NB, 256, 0, stream>>>(deg, bsum, N);
    scanB_kernel<<<1, 256, 0, stream>>>(bsum, boff, NB);
    scanC_kernel<<<NB, 256, 0, stream>>>(deg, boff, row_ptr, N);
    fill_kernel<<<512, 256, 0, stream>>>(esrc, edst, esh, row_ptr, cur,
                                         csr2edge, src_s, sh_s, E);
    edge_w_kernel<<<512, 512, 0, stream>>>(escal, csr2edge, Wfc1, Wfc2, w_s, E);
    gather_post_kernel<<<4096, 256, 0, stream>>>(w_s, src_s, sh_s, row_ptr,
                                                 y, attr, Wl20, Wl21, Walpha,
                                                 out, N);
}